// Round 7
// baseline (1866.963 us; speedup 1.0000x reference)
//
#include <hip/hip_runtime.h>

#define NN 50000
#define EE 800000
#define DD 256
#define CC 4
#define BN_EPSF 1e-5f
#define MROWS 48
#define ZPAD 268  // f32 row stride: 1072B = 16B-aligned, 2-way-bank-safe for frag reads

typedef float v4f __attribute__((ext_vector_type(4)));
typedef float f32x4 __attribute__((ext_vector_type(4)));
typedef __bf16 bf16x8 __attribute__((ext_vector_type(8)));
typedef _Float16 h4 __attribute__((ext_vector_type(4)));

// ---------------- cluster partition ----------------

// per-node cluster id -> compacted per-cluster node lists; pcl[i] = (c<<28)|listpos
__global__ void k_compact(const float* __restrict__ masks, int* __restrict__ ncount,
                          int* __restrict__ nlist, int* __restrict__ pcl) {
  int i = blockIdx.x * 256 + threadIdx.x;
  if (i >= NN) return;
  int c = 0;
#pragma unroll
  for (int k = 1; k < CC; ++k)
    if (masks[(size_t)k * NN + i] > 0.5f) c = k;
  int li = atomicAdd(&ncount[c], 1);
  nlist[c * NN + li] = i;
  pcl[i] = (c << 28) | li;
}

// 1 block: bases from ncount (thread 0) + affine-state init (all threads)
__global__ void k_setup(const int* __restrict__ ncount, int* __restrict__ base,
                        float* __restrict__ Pg, float* __restrict__ Qg,
                        float* __restrict__ tblA, float* __restrict__ tblB) {
  int d = threadIdx.x;
  if (d == 0) {
    int b = 0;
#pragma unroll
    for (int c = 0; c < CC; ++c) { base[c] = b; b += ncount[c]; }
  }
  Pg[d] = 1.f;
  Qg[d] = 0.f;
#pragma unroll
  for (int m = 0; m < CC; ++m) {
    tblA[m * DD + d] = 1.f;
    tblB[m * DD + d] = 0.f;
  }
}

// ---------------- CSR build (rows ordered by (cluster, listpos)) ----------------

__global__ void k_hist(const int* __restrict__ dst, const int* __restrict__ pcl,
                       const int* __restrict__ base, int* __restrict__ cnt) {
  int e = blockIdx.x * 256 + threadIdx.x;
  if (e < EE) {
    int pc = pcl[dst[e]];
    atomicAdd(&cnt[base[pc >> 28] + (pc & 0x0FFFFFFF)], 1);
  }
}

// single-block exclusive scan of cnt[0..NN) -> rp[0..NN], and cnt[i] := exclusive (cursor init)
__global__ void k_scan(int* __restrict__ cnt, int* __restrict__ rp) {
  __shared__ int wsums[16];
  __shared__ int sh_carry;
  __shared__ int sh_ctot;
  const int t = threadIdx.x;
  const int lane = t & 63;
  const int w = t >> 6;
  if (t == 0) sh_carry = 0;
  __syncthreads();
  for (int base = 0; base < NN; base += 1024) {
    int i = base + t;
    int v = (i < NN) ? cnt[i] : 0;
    int incl = v;
#pragma unroll
    for (int off = 1; off < 64; off <<= 1) {
      int u = __shfl_up(incl, off, 64);
      if (lane >= off) incl += u;
    }
    if (lane == 63) wsums[w] = incl;
    int cbase = sh_carry;
    __syncthreads();
    if (w == 0) {
      int s = (lane < 16) ? wsums[lane] : 0;
      int si = s;
#pragma unroll
      for (int off = 1; off < 16; off <<= 1) {
        int u = __shfl_up(si, off, 64);
        if (lane >= off) si += u;
      }
      if (lane < 16) wsums[lane] = si - s;  // exclusive wave offset
      if (lane == 15) sh_ctot = si;         // chunk total
    }
    __syncthreads();
    int excl = cbase + wsums[w] + (incl - v);
    if (i < NN) { rp[i] = excl; cnt[i] = excl; }
    __syncthreads();
    if (t == 0) sh_carry = cbase + sh_ctot;
    __syncthreads();
  }
  if (t == 0) rp[NN] = sh_carry;
}

// thread per edge: slot p via atomic cursor; sse[p] = ((cluster(src)<<24)|src, e)
__global__ void k_scatter(const int* __restrict__ src, const int* __restrict__ dst,
                          const int* __restrict__ pcl, const int* __restrict__ base,
                          int* __restrict__ cur, int2* __restrict__ sse) {
  int e = blockIdx.x * 256 + threadIdx.x;
  if (e < EE) {
    int s = src[e];
    int pcd = pcl[dst[e]];
    int g = base[pcd >> 28] + (pcd & 0x0FFFFFFF);
    int p = atomicAdd(&cur[g], 1);
    int ms = ((unsigned)pcl[s]) >> 28;
    sse[p] = make_int2((ms << 24) | s, e);
  }
}

// ---------------- weight pre-format: frag-linear bf16 hi/lo ----------------
// layout per (c,mat): [half(2)][kk(8)][cg(16)][lane(64)][j(8)] bf16; 65536 bf16 per half.
// frag element: lane l holds W[kk*32 + 8*(l>>4) + j][cg*16 + (l&15)]  (B-operand layout)
__global__ void k_wfmt(const float* __restrict__ W1, const float* __restrict__ W2,
                       __bf16* __restrict__ wf) {
  int b = blockIdx.x;  // 64 blocks = c(4) x mat(2) x kk(8)
  int c = b >> 4, mat = (b >> 3) & 1, kk = b & 7;
  const float* W = (mat ? W2 : W1) + (size_t)c * DD * DD;
  __bf16* base = wf + (size_t)(c * 2 + mat) * 2 * 65536;
  int t = threadIdx.x;
  int lane = t & 63, cq = t >> 6;
  int l4 = lane >> 4, l16 = lane & 15;
#pragma unroll
  for (int ci = 0; ci < 4; ++ci) {
    int cg = cq * 4 + ci;
    bf16x8 hi, lo;
#pragma unroll
    for (int j = 0; j < 8; ++j) {
      float v = W[(size_t)(kk * 32 + l4 * 8 + j) * DD + cg * 16 + l16];
      __bf16 h = (__bf16)v;
      hi[j] = h;
      lo[j] = (__bf16)(v - (float)h);
    }
    size_t off = ((size_t)(kk * 16 + cg) * 64 + lane) * 8;
    *(bf16x8*)(base + off) = hi;
    *(bf16x8*)(base + 65536 + off) = lo;
  }
}

// ---------------- helpers ----------------

__device__ __forceinline__ v4f relu4(v4f s) {
  s.x = fmaxf(s.x, 0.f); s.y = fmaxf(s.y, 0.f);
  s.z = fmaxf(s.z, 0.f); s.w = fmaxf(s.w, 0.f);
  return s;
}

// prologue: g16 = fp16(x_in); per-cluster sums s01[m] = sum(x0), s02[m] = sum(x0^2)
__global__ __launch_bounds__(256) void k_prep(
    const float* __restrict__ xin, const int* __restrict__ pcl,
    _Float16* __restrict__ g16, float* __restrict__ s01, float* __restrict__ s02) {
  __shared__ float s1[CC][DD];
  __shared__ float s2[CC][DD];
  const int t = threadIdx.x;
  const int lane = t & 63;
#pragma unroll
  for (int j = 0; j < CC; ++j) { s1[j][t] = 0.f; s2[j][t] = 0.f; }
  __syncthreads();
  const int c4 = lane << 2;
  const int wid0 = (blockIdx.x * 256 + t) >> 6;
  const int wstride = gridDim.x * 4;
  for (int i = wid0; i < NN; i += wstride) {
    int m = ((unsigned)pcl[i]) >> 28;
    v4f xv = ((const v4f*)(xin + (size_t)i * DD))[lane];
    h4 h;
    h.x = (_Float16)xv.x; h.y = (_Float16)xv.y;
    h.z = (_Float16)xv.z; h.w = (_Float16)xv.w;
    ((h4*)(g16 + (size_t)i * DD))[lane] = h;
    atomicAdd(&s1[m][c4 + 0], xv.x);
    atomicAdd(&s1[m][c4 + 1], xv.y);
    atomicAdd(&s1[m][c4 + 2], xv.z);
    atomicAdd(&s1[m][c4 + 3], xv.w);
    atomicAdd(&s2[m][c4 + 0], xv.x * xv.x);
    atomicAdd(&s2[m][c4 + 1], xv.y * xv.y);
    atomicAdd(&s2[m][c4 + 2], xv.z * xv.z);
    atomicAdd(&s2[m][c4 + 3], xv.w * xv.w);
  }
  __syncthreads();
#pragma unroll
  for (int j = 0; j < CC; ++j) {
    atomicAdd(&s01[j * DD + t], s1[j][t]);
    atomicAdd(&s02[j * DD + t], s2[j][t]);
  }
}

// One wave per cluster row g=base[c]+li: aggrc[li] = sum over slots of
// relu(affine_state(g16[src]) + ea[e]).
// 8-edge groups: all 16 gathers issued before any consume (memory-level parallelism);
// launch_bounds(256,4) pins VGPR<=128 so occupancy stays 4 waves/SIMD.
__global__ __launch_bounds__(256, 4) void k_aggregate_m(
    const _Float16* __restrict__ g16, const float* __restrict__ ea,
    const int* __restrict__ rp, const int2* __restrict__ sse,
    const int* __restrict__ basep, const int* __restrict__ ncount,
    const float* __restrict__ tblA, const float* __restrict__ tblB,
    int cidx, float* __restrict__ aggrc) {
  int li = (blockIdx.x * 256 + threadIdx.x) >> 6;
  int lane = threadIdx.x & 63;
  if (li >= ncount[cidx]) return;
  v4f A0 = ((const v4f*)(tblA + 0 * DD))[lane];
  v4f A1 = ((const v4f*)(tblA + 1 * DD))[lane];
  v4f A2 = ((const v4f*)(tblA + 2 * DD))[lane];
  v4f A3 = ((const v4f*)(tblA + 3 * DD))[lane];
  v4f B0 = ((const v4f*)(tblB + 0 * DD))[lane];
  v4f B1 = ((const v4f*)(tblB + 1 * DD))[lane];
  v4f B2 = ((const v4f*)(tblB + 2 * DD))[lane];
  v4f B3 = ((const v4f*)(tblB + 3 * DD))[lane];
  int g = basep[cidx] + li;
  int beg = rp[g], end = rp[g + 1];
  v4f acc = {0.f, 0.f, 0.f, 0.f};
  int p = beg;
  for (; p + 8 <= end; p += 8) {
    int2 d[8];
#pragma unroll
    for (int j = 0; j < 8; ++j) d[j] = sse[p + j];
    v4f av[8];
    h4 xv[8];
#pragma unroll
    for (int j = 0; j < 8; ++j)
      av[j] = __builtin_nontemporal_load(((const v4f*)(ea + (size_t)d[j].y * DD)) + lane);
#pragma unroll
    for (int j = 0; j < 8; ++j)
      xv[j] = ((const h4*)(g16 + (size_t)(d[j].x & 0x00FFFFFF) * DD))[lane];
#pragma unroll
    for (int j = 0; j < 8; ++j) {
      int m = ((unsigned)d[j].x) >> 24;
      v4f Aa = (m & 2) ? ((m & 1) ? A3 : A2) : ((m & 1) ? A1 : A0);
      v4f Ba = (m & 2) ? ((m & 1) ? B3 : B2) : ((m & 1) ? B1 : B0);
      acc += relu4(Aa * __builtin_convertvector(xv[j], v4f) + Ba + av[j]);
    }
  }
  if (p + 4 <= end) {
    int2 d[4];
#pragma unroll
    for (int j = 0; j < 4; ++j) d[j] = sse[p + j];
    v4f av[4];
    h4 xv[4];
#pragma unroll
    for (int j = 0; j < 4; ++j)
      av[j] = __builtin_nontemporal_load(((const v4f*)(ea + (size_t)d[j].y * DD)) + lane);
#pragma unroll
    for (int j = 0; j < 4; ++j)
      xv[j] = ((const h4*)(g16 + (size_t)(d[j].x & 0x00FFFFFF) * DD))[lane];
#pragma unroll
    for (int j = 0; j < 4; ++j) {
      int m = ((unsigned)d[j].x) >> 24;
      v4f Aa = (m & 2) ? ((m & 1) ? A3 : A2) : ((m & 1) ? A1 : A0);
      v4f Ba = (m & 2) ? ((m & 1) ? B3 : B2) : ((m & 1) ? B1 : B0);
      acc += relu4(Aa * __builtin_convertvector(xv[j], v4f) + Ba + av[j]);
    }
    p += 4;
  }
  for (; p < end; ++p) {
    int2 d0 = sse[p];
    v4f a0 = __builtin_nontemporal_load(((const v4f*)(ea + (size_t)d0.y * DD)) + lane);
    h4 x0 = ((const h4*)(g16 + (size_t)(d0.x & 0x00FFFFFF) * DD))[lane];
    int m0 = ((unsigned)d0.x) >> 24;
    v4f Aa = (m0 & 2) ? ((m0 & 1) ? A3 : A2) : ((m0 & 1) ? A1 : A0);
    v4f Ba = (m0 & 2) ? ((m0 & 1) ? B3 : B2) : ((m0 & 1) ? B1 : B0);
    acc += relu4(Aa * __builtin_convertvector(x0, v4f) + Ba + a0);
  }
  ((v4f*)(aggrc + (size_t)li * DD))[lane] = acc;
}

// split-bf16 MFMA GEMM: acc[3][4] (48 rows x 64 cols per wave) = bias + zb(48x256) @ W(256x256)
__device__ __forceinline__ void gemm_frag(
    const float (*zb)[ZPAD], const __bf16* __restrict__ wf,
    const float* __restrict__ bias, f32x4 (&acc)[3][4], int w, int lane) {
  const int l4 = lane >> 4, l16 = lane & 15;
#pragma unroll
  for (int cg = 0; cg < 4; ++cg) {
    float bv = bias[w * 64 + cg * 16 + l16];
    f32x4 b4 = {bv, bv, bv, bv};
#pragma unroll
    for (int mg = 0; mg < 3; ++mg) acc[mg][cg] = b4;
  }
  for (int kk = 0; kk < 8; ++kk) {
    bf16x8 bh[4], bl[4];
#pragma unroll
    for (int cg = 0; cg < 4; ++cg) {
      const __bf16* p = wf + (((size_t)(kk * 16 + w * 4 + cg)) * 64 + lane) * 8;
      bh[cg] = *(const bf16x8*)p;
      bl[cg] = *(const bf16x8*)(p + 65536);
    }
#pragma unroll
    for (int mg = 0; mg < 3; ++mg) {
      const float* zp = &zb[mg * 16 + l16][kk * 32 + l4 * 8];
      float4 z0 = *(const float4*)zp;
      float4 z1 = *(const float4*)(zp + 4);
      float zv[8] = {z0.x, z0.y, z0.z, z0.w, z1.x, z1.y, z1.z, z1.w};
      bf16x8 ah, al;
#pragma unroll
      for (int j = 0; j < 8; ++j) {
        __bf16 h = (__bf16)zv[j];
        ah[j] = h;
        al[j] = (__bf16)(zv[j] - (float)h);
      }
#pragma unroll
      for (int cg = 0; cg < 4; ++cg) {
        acc[mg][cg] = __builtin_amdgcn_mfma_f32_16x16x32_bf16(al, bh[cg], acc[mg][cg], 0, 0, 0);
        acc[mg][cg] = __builtin_amdgcn_mfma_f32_16x16x32_bf16(ah, bl[cg], acc[mg][cg], 0, 0, 0);
        acc[mg][cg] = __builtin_amdgcn_mfma_f32_16x16x32_bf16(ah, bh[cg], acc[mg][cg], 0, 0, 0);
      }
    }
  }
}

// Masked-rows MLP for pass c. Cluster-c rows are unhit: x_c = P*x0 + Q (x0 = x_in, fp32).
// z=(1+eps)x_c+aggr; t=relu(z@W1+b1); h=t@W2+b2; v = x_c + h (pre-norm y).
// Writes xbase[nid]=v (fp32), g16[nid]=fp16(v); accumulates sum(v), sum(v^2) into sv1,sv2.
__global__ __launch_bounds__(256, 2) void k_mlp_m(
    const float* __restrict__ xin, const float* __restrict__ aggrc,
    float* __restrict__ xbase, _Float16* __restrict__ g16,
    const __bf16* __restrict__ wf1, const __bf16* __restrict__ wf2,
    const float* __restrict__ b1g, const float* __restrict__ b2g,
    const int* __restrict__ nlist_c, const int* __restrict__ ncnt_c,
    const float* __restrict__ epsp, const float* __restrict__ Pg,
    const float* __restrict__ Qg,
    float* __restrict__ sv1c, float* __restrict__ sv2c) {
  __shared__ __align__(16) float zbuf[MROWS][ZPAD];
  __shared__ float ssum[DD];
  __shared__ float ssq[DD];
  __shared__ int nls[MROWS];
  const int t = threadIdx.x;
  const int lane = t & 63, w = t >> 6;
  const int l4 = lane >> 4, l16 = lane & 15;
  const int ncnt = *ncnt_c;
  const int li0 = blockIdx.x * MROWS;
  if (li0 >= ncnt) return;
  if (t < MROWS) nls[t] = (li0 + t < ncnt) ? nlist_c[li0 + t] : -1;
  ssum[t] = 0.f;
  ssq[t] = 0.f;
  const float ep = 1.0f + epsp[0];
  __syncthreads();
  // stage z = ep*(P*x0+Q) + aggr (fp32, coalesced float4)
  const int c4s = (t & 63) << 2;
  const float4 Pv4 = *(const float4*)(Pg + c4s);
  const float4 Qv4 = *(const float4*)(Qg + c4s);
#pragma unroll
  for (int i = 0; i < 12; ++i) {
    int f4 = t + 256 * i;  // 3072 float4 = 48x256
    int r = f4 >> 6;
    int nid = nls[r];
    float4 zv = make_float4(0.f, 0.f, 0.f, 0.f);
    if (nid >= 0) {
      float4 xv = *(const float4*)(xin + (size_t)nid * DD + c4s);
      float4 av = *(const float4*)(aggrc + (size_t)(li0 + r) * DD + c4s);
      zv.x = fmaf(ep, fmaf(Pv4.x, xv.x, Qv4.x), av.x);
      zv.y = fmaf(ep, fmaf(Pv4.y, xv.y, Qv4.y), av.y);
      zv.z = fmaf(ep, fmaf(Pv4.z, xv.z, Qv4.z), av.z);
      zv.w = fmaf(ep, fmaf(Pv4.w, xv.w, Qv4.w), av.w);
    }
    *(float4*)&zbuf[r][c4s] = zv;
  }
  __syncthreads();
  f32x4 acc[3][4];
  gemm_frag(zbuf, wf1, b1g, acc, w, lane);
  __syncthreads();  // all zbuf reads of GEMM1 done
  // t = relu(.) written back to zbuf (D layout: row=(l>>4)*4+r, col=l&15)
#pragma unroll
  for (int mg = 0; mg < 3; ++mg)
#pragma unroll
    for (int cg = 0; cg < 4; ++cg)
#pragma unroll
      for (int r = 0; r < 4; ++r)
        zbuf[mg * 16 + l4 * 4 + r][w * 64 + cg * 16 + l16] = fmaxf(acc[mg][cg][r], 0.f);
  __syncthreads();
  f32x4 acc2[3][4];
  gemm_frag(zbuf, wf2, b2g, acc2, w, lane);
  // epilogue: v = (P*x0+Q) + h; write xbase/g16; sums of v, v^2
  float Pv[4], Qv[4], ps[4], pq[4];
#pragma unroll
  for (int cg = 0; cg < 4; ++cg) {
    int col = w * 64 + cg * 16 + l16;
    Pv[cg] = Pg[col];
    Qv[cg] = Qg[col];
    ps[cg] = 0.f;
    pq[cg] = 0.f;
  }
#pragma unroll
  for (int mg = 0; mg < 3; ++mg) {
#pragma unroll
    for (int r = 0; r < 4; ++r) {
      int rb = mg * 16 + l4 * 4 + r;
      int nid = nls[rb];
      if (nid >= 0) {
#pragma unroll
        for (int cg = 0; cg < 4; ++cg) {
          int col = w * 64 + cg * 16 + l16;
          float x0v = xin[(size_t)nid * DD + col];
          float xcv = fmaf(Pv[cg], x0v, Qv[cg]);
          float v = xcv + acc2[mg][cg][r];
          xbase[(size_t)nid * DD + col] = v;
          g16[(size_t)nid * DD + col] = (_Float16)v;
          ps[cg] += v;
          pq[cg] += v * v;
        }
      }
    }
  }
#pragma unroll
  for (int cg = 0; cg < 4; ++cg) {
    atomicAdd(&ssum[w * 64 + cg * 16 + l16], ps[cg]);
    atomicAdd(&ssq[w * 64 + cg * 16 + l16], pq[cg]);
  }
  __syncthreads();
  atomicAdd(&sv1c[t], ssum[t]);
  atomicAdd(&sv2c[t], ssq[t]);
}

// Per-pass BN stats from composed group sums + affine-chain update. 1 block, DD threads.
__global__ void k_stats(const float* __restrict__ s01, const float* __restrict__ s02,
                        const float* __restrict__ sv1, const float* __restrict__ sv2,
                        const int* __restrict__ ncount,
                        const float* __restrict__ gamma_c, const float* __restrict__ beta_c,
                        float* __restrict__ Pg, float* __restrict__ Qg,
                        float* __restrict__ Rg, float* __restrict__ Sg,
                        float* __restrict__ tblA, float* __restrict__ tblB, int c) {
  int d = threadIdx.x;
  float Pd = Pg[d], Qd = Qg[d];
  float sum = 0.f, ssq = 0.f;
#pragma unroll
  for (int m = 0; m < CC; ++m) {
    float n = (float)ncount[m];
    if (m < c) {
      float A = Rg[m * DD + d], B = Sg[m * DD + d];
      sum += fmaf(A, sv1[m * DD + d], n * B);
      ssq += A * A * sv2[m * DD + d] + 2.f * A * B * sv1[m * DD + d] + n * B * B;
    } else if (m == c) {
      sum += sv1[m * DD + d];
      ssq += sv2[m * DD + d];
    } else {
      sum += fmaf(Pd, s01[m * DD + d], n * Qd);
      ssq += Pd * Pd * s02[m * DD + d] + 2.f * Pd * Qd * s01[m * DD + d] + n * Qd * Qd;
    }
  }
  const float inv_n = 1.0f / (float)NN;
  float mean = sum * inv_n;
  float var = fmaxf(ssq * inv_n - mean * mean, 0.f);
  float sc = gamma_c[d] * rsqrtf(var + BN_EPSF);
  float sh = fmaf(-mean, sc, beta_c[d]);
  // update chains (x_{c+1} = sc*y_c + sh)
  float Pn = sc * Pd, Qn = fmaf(sc, Qd, sh);
  Pg[d] = Pn;
  Qg[d] = Qn;
#pragma unroll
  for (int m = 0; m < CC; ++m) {
    if (m < c) {
      float Rn = sc * Rg[m * DD + d];
      float Sn = fmaf(sc, Sg[m * DD + d], sh);
      Rg[m * DD + d] = Rn;
      Sg[m * DD + d] = Sn;
      tblA[m * DD + d] = Rn;
      tblB[m * DD + d] = Sn;
    } else if (m == c) {
      Rg[m * DD + d] = sc;
      Sg[m * DD + d] = sh;
      tblA[m * DD + d] = sc;
      tblB[m * DD + d] = sh;
    } else {
      tblA[m * DD + d] = Pn;
      tblB[m * DD + d] = Qn;
    }
  }
}

// final: out = x_in + relu(R_m * v + S_m)  (all nodes hit; tbl holds R,S after pass 3)
__global__ __launch_bounds__(256) void k_final(
    const float* __restrict__ xbase, const int* __restrict__ pcl,
    const float* __restrict__ tblA, const float* __restrict__ tblB,
    const float* __restrict__ xin, float* __restrict__ outp) {
  const int t = threadIdx.x;
  const int lane = t & 63;
  const int wid0 = (blockIdx.x * 256 + t) >> 6;
  const int wstride = gridDim.x * 4;
  for (int i = wid0; i < NN; i += wstride) {
    int m = ((unsigned)pcl[i]) >> 28;
    v4f v = ((const v4f*)(xbase + (size_t)i * DD))[lane];
    v4f A = ((const v4f*)(tblA + (size_t)m * DD))[lane];
    v4f B = ((const v4f*)(tblB + (size_t)m * DD))[lane];
    v4f xi = ((const v4f*)(xin + (size_t)i * DD))[lane];
    ((v4f*)(outp + (size_t)i * DD))[lane] = xi + relu4(A * v + B);
  }
}

// ---------------- launch ----------------

extern "C" void kernel_launch(void* const* d_in, const int* in_sizes, int n_in,
                              void* d_out, int out_size, void* d_ws, size_t ws_size,
                              hipStream_t stream) {
  (void)in_sizes; (void)n_in; (void)out_size; (void)ws_size;
  const float* x_in  = (const float*)d_in[0];
  const int*   ei    = (const int*)d_in[1];
  const float* ea    = (const float*)d_in[2];
  const float* masks = (const float*)d_in[3];
  // d_in[4] = complement_masks: unused by the reference
  const float* W1    = (const float*)d_in[5];
  const float* b1    = (const float*)d_in[6];
  const float* W2    = (const float*)d_in[7];
  const float* b2    = (const float*)d_in[8];
  const float* eps   = (const float*)d_in[9];
  const float* gamma = (const float*)d_in[10];
  const float* beta  = (const float*)d_in[11];
  float* out = (float*)d_out;

  // workspace layout (all 16B-aligned); ~140 MB
  float* xbase = (float*)d_ws;                        // NN*DD (per-node pre-norm y_m)
  float* aggrc = xbase + (size_t)NN * DD;             // NN*DD (compact aggregates)
  _Float16* g16 = (_Float16*)(aggrc + (size_t)NN * DD);  // NN*DD fp16 gather base
  int2*  sse   = (int2*)(g16 + (size_t)NN * DD);      // EE ((cl<<24)|src, e) per slot
  int*   rp    = (int*)(sse + EE);                    // NN+1 (padded to 50016)
  int*   cnt   = rp + 50016;                          // NN (padded), also scatter cursor
  int*   nlist = cnt + 50016;                         // CC*NN (compacted node lists)
  int*   pcl   = nlist + CC * NN;                     // NN packed (c<<28)|listpos
  int*   ncount = pcl + NN;                           // CC (padded to 16)
  int*   base  = ncount + 16;                         // CC (padded to 16)
  float* s01   = (float*)(base + 16);                 // CC*DD sum(x0) per cluster
  float* s02   = s01 + CC * DD;                       // CC*DD sum(x0^2)
  float* sv1   = s02 + CC * DD;                       // CC*DD sum(v_m)
  float* sv2   = sv1 + CC * DD;                       // CC*DD sum(v_m^2)
  float* Pg    = sv2 + CC * DD;                       // DD unhit-chain scale
  float* Qg    = Pg + DD;                             // DD unhit-chain shift
  float* Rg    = Qg + DD;                             // CC*DD hit-chain scale
  float* Sg    = Rg + CC * DD;                        // CC*DD hit-chain shift
  float* tblA  = Sg + CC * DD;                        // CC*DD aggregate coeff A
  float* tblB  = tblA + CC * DD;                      // CC*DD aggregate coeff B
  __bf16* wfmt = (__bf16*)(tblB + CC * DD);           // 4*2*2*65536 bf16 = 2 MB

  const int* src = ei;
  const int* dst = ei + EE;

  hipMemsetAsync(cnt, 0, NN * sizeof(int), stream);
  hipMemsetAsync(ncount, 0, 32 * sizeof(int), stream);
  hipMemsetAsync(s01, 0, 4 * CC * DD * sizeof(float), stream);  // s01,s02,sv1,sv2

  k_wfmt<<<64, 256, 0, stream>>>(W1, W2, wfmt);
  k_compact<<<(NN + 255) / 256, 256, 0, stream>>>(masks, ncount, nlist, pcl);
  k_setup<<<1, DD, 0, stream>>>(ncount, base, Pg, Qg, tblA, tblB);
  k_hist<<<EE / 256, 256, 0, stream>>>(dst, pcl, base, cnt);
  k_scan<<<1, 1024, 0, stream>>>(cnt, rp);
  k_scatter<<<EE / 256, 256, 0, stream>>>(src, dst, pcl, base, cnt, sse);
  k_prep<<<256, 256, 0, stream>>>(x_in, pcl, g16, s01, s02);

  for (int c = 0; c < CC; ++c) {
    k_aggregate_m<<<(NN * 64 + 255) / 256, 256, 0, stream>>>(
        g16, ea, rp, sse, base, ncount, tblA, tblB, c, aggrc);
    k_mlp_m<<<(NN + MROWS - 1) / MROWS, 256, 0, stream>>>(
        x_in, aggrc, xbase, g16,
        wfmt + (size_t)(c * 2 + 0) * 2 * 65536,
        wfmt + (size_t)(c * 2 + 1) * 2 * 65536,
        b1 + (size_t)c * DD, b2 + (size_t)c * DD,
        nlist + c * NN, ncount + c, eps + c, Pg, Qg,
        sv1 + c * DD, sv2 + c * DD);
    k_stats<<<1, DD, 0, stream>>>(s01, s02, sv1, sv2, ncount,
                                  gamma + (size_t)c * DD, beta + (size_t)c * DD,
                                  Pg, Qg, Rg, Sg, tblA, tblB, c);
  }
  k_final<<<512, 256, 0, stream>>>(xbase, pcl, tblA, tblB, x_in, out);
}

// Round 8
// 1836.244 us; speedup vs baseline: 1.0167x; 1.0167x over previous
//
#include <hip/hip_runtime.h>

#define NN 50000
#define EE 800000
#define DD 256
#define CC 4
#define BN_EPSF 1e-5f
#define MROWS 48
#define ZPAD 268  // f32 row stride: 1072B = 16B-aligned, 2-way-bank-safe for frag reads

typedef float v4f __attribute__((ext_vector_type(4)));
typedef float f32x4 __attribute__((ext_vector_type(4)));
typedef __bf16 bf16x8 __attribute__((ext_vector_type(8)));
typedef _Float16 h4 __attribute__((ext_vector_type(4)));

// ---------------- cluster partition ----------------

// per-node cluster id -> compacted per-cluster node lists; pcl[i] = (c<<28)|listpos
__global__ void k_compact(const float* __restrict__ masks, int* __restrict__ ncount,
                          int* __restrict__ nlist, int* __restrict__ pcl) {
  int i = blockIdx.x * 256 + threadIdx.x;
  if (i >= NN) return;
  int c = 0;
#pragma unroll
  for (int k = 1; k < CC; ++k)
    if (masks[(size_t)k * NN + i] > 0.5f) c = k;
  int li = atomicAdd(&ncount[c], 1);
  nlist[c * NN + li] = i;
  pcl[i] = (c << 28) | li;
}

// 1 block: bases from ncount (thread 0) + affine-state init (all threads)
__global__ void k_setup(const int* __restrict__ ncount, int* __restrict__ base,
                        float* __restrict__ Pg, float* __restrict__ Qg,
                        float* __restrict__ tblA, float* __restrict__ tblB) {
  int d = threadIdx.x;
  if (d == 0) {
    int b = 0;
#pragma unroll
    for (int c = 0; c < CC; ++c) { base[c] = b; b += ncount[c]; }
  }
  Pg[d] = 1.f;
  Qg[d] = 0.f;
#pragma unroll
  for (int m = 0; m < CC; ++m) {
    tblA[m * DD + d] = 1.f;
    tblB[m * DD + d] = 0.f;
  }
}

// ---------------- CSR build (rows ordered by (cluster, listpos)) ----------------

__global__ void k_hist(const int* __restrict__ dst, const int* __restrict__ pcl,
                       const int* __restrict__ base, int* __restrict__ cnt) {
  int e = blockIdx.x * 256 + threadIdx.x;
  if (e < EE) {
    int pc = pcl[dst[e]];
    atomicAdd(&cnt[base[pc >> 28] + (pc & 0x0FFFFFFF)], 1);
  }
}

// single-block exclusive scan of cnt[0..NN) -> rp[0..NN], and cnt[i] := exclusive (cursor init)
__global__ void k_scan(int* __restrict__ cnt, int* __restrict__ rp) {
  __shared__ int wsums[16];
  __shared__ int sh_carry;
  __shared__ int sh_ctot;
  const int t = threadIdx.x;
  const int lane = t & 63;
  const int w = t >> 6;
  if (t == 0) sh_carry = 0;
  __syncthreads();
  for (int base = 0; base < NN; base += 1024) {
    int i = base + t;
    int v = (i < NN) ? cnt[i] : 0;
    int incl = v;
#pragma unroll
    for (int off = 1; off < 64; off <<= 1) {
      int u = __shfl_up(incl, off, 64);
      if (lane >= off) incl += u;
    }
    if (lane == 63) wsums[w] = incl;
    int cbase = sh_carry;
    __syncthreads();
    if (w == 0) {
      int s = (lane < 16) ? wsums[lane] : 0;
      int si = s;
#pragma unroll
      for (int off = 1; off < 16; off <<= 1) {
        int u = __shfl_up(si, off, 64);
        if (lane >= off) si += u;
      }
      if (lane < 16) wsums[lane] = si - s;  // exclusive wave offset
      if (lane == 15) sh_ctot = si;         // chunk total
    }
    __syncthreads();
    int excl = cbase + wsums[w] + (incl - v);
    if (i < NN) { rp[i] = excl; cnt[i] = excl; }
    __syncthreads();
    if (t == 0) sh_carry = cbase + sh_ctot;
    __syncthreads();
  }
  if (t == 0) rp[NN] = sh_carry;
}

// thread per edge: slot p via atomic cursor; sse[p] = ((cluster(src)<<24)|src, e)
__global__ void k_scatter(const int* __restrict__ src, const int* __restrict__ dst,
                          const int* __restrict__ pcl, const int* __restrict__ base,
                          int* __restrict__ cur, int2* __restrict__ sse) {
  int e = blockIdx.x * 256 + threadIdx.x;
  if (e < EE) {
    int s = src[e];
    int pcd = pcl[dst[e]];
    int g = base[pcd >> 28] + (pcd & 0x0FFFFFFF);
    int p = atomicAdd(&cur[g], 1);
    int ms = ((unsigned)pcl[s]) >> 28;
    sse[p] = make_int2((ms << 24) | s, e);
  }
}

// ---------------- weight pre-format: frag-linear bf16 hi/lo ----------------
// layout per (c,mat): [half(2)][kk(8)][cg(16)][lane(64)][j(8)] bf16; 65536 bf16 per half.
// frag element: lane l holds W[kk*32 + 8*(l>>4) + j][cg*16 + (l&15)]  (B-operand layout)
__global__ void k_wfmt(const float* __restrict__ W1, const float* __restrict__ W2,
                       __bf16* __restrict__ wf) {
  int b = blockIdx.x;  // 64 blocks = c(4) x mat(2) x kk(8)
  int c = b >> 4, mat = (b >> 3) & 1, kk = b & 7;
  const float* W = (mat ? W2 : W1) + (size_t)c * DD * DD;
  __bf16* base = wf + (size_t)(c * 2 + mat) * 2 * 65536;
  int t = threadIdx.x;
  int lane = t & 63, cq = t >> 6;
  int l4 = lane >> 4, l16 = lane & 15;
#pragma unroll
  for (int ci = 0; ci < 4; ++ci) {
    int cg = cq * 4 + ci;
    bf16x8 hi, lo;
#pragma unroll
    for (int j = 0; j < 8; ++j) {
      float v = W[(size_t)(kk * 32 + l4 * 8 + j) * DD + cg * 16 + l16];
      __bf16 h = (__bf16)v;
      hi[j] = h;
      lo[j] = (__bf16)(v - (float)h);
    }
    size_t off = ((size_t)(kk * 16 + cg) * 64 + lane) * 8;
    *(bf16x8*)(base + off) = hi;
    *(bf16x8*)(base + 65536 + off) = lo;
  }
}

// ---------------- helpers ----------------

__device__ __forceinline__ v4f relu4(v4f s) {
  s.x = fmaxf(s.x, 0.f); s.y = fmaxf(s.y, 0.f);
  s.z = fmaxf(s.z, 0.f); s.w = fmaxf(s.w, 0.f);
  return s;
}

// prologue: g16 = fp16(x_in); per-cluster sums s01[m] = sum(x0), s02[m] = sum(x0^2)
__global__ __launch_bounds__(256) void k_prep(
    const float* __restrict__ xin, const int* __restrict__ pcl,
    _Float16* __restrict__ g16, float* __restrict__ s01, float* __restrict__ s02) {
  __shared__ float s1[CC][DD];
  __shared__ float s2[CC][DD];
  const int t = threadIdx.x;
  const int lane = t & 63;
#pragma unroll
  for (int j = 0; j < CC; ++j) { s1[j][t] = 0.f; s2[j][t] = 0.f; }
  __syncthreads();
  const int c4 = lane << 2;
  const int wid0 = (blockIdx.x * 256 + t) >> 6;
  const int wstride = gridDim.x * 4;
  for (int i = wid0; i < NN; i += wstride) {
    int m = ((unsigned)pcl[i]) >> 28;
    v4f xv = ((const v4f*)(xin + (size_t)i * DD))[lane];
    h4 h;
    h.x = (_Float16)xv.x; h.y = (_Float16)xv.y;
    h.z = (_Float16)xv.z; h.w = (_Float16)xv.w;
    ((h4*)(g16 + (size_t)i * DD))[lane] = h;
    atomicAdd(&s1[m][c4 + 0], xv.x);
    atomicAdd(&s1[m][c4 + 1], xv.y);
    atomicAdd(&s1[m][c4 + 2], xv.z);
    atomicAdd(&s1[m][c4 + 3], xv.w);
    atomicAdd(&s2[m][c4 + 0], xv.x * xv.x);
    atomicAdd(&s2[m][c4 + 1], xv.y * xv.y);
    atomicAdd(&s2[m][c4 + 2], xv.z * xv.z);
    atomicAdd(&s2[m][c4 + 3], xv.w * xv.w);
  }
  __syncthreads();
#pragma unroll
  for (int j = 0; j < CC; ++j) {
    atomicAdd(&s01[j * DD + t], s1[j][t]);
    atomicAdd(&s02[j * DD + t], s2[j][t]);
  }
}

// One wave per cluster row g=base[c]+li: aggrc16[li] = fp16(sum over slots of
// relu(affine_state(g16[src]) + ea[e])); affine coeffs selected by src's cluster state.
__global__ __launch_bounds__(256, 4) void k_aggregate_m(
    const _Float16* __restrict__ g16, const float* __restrict__ ea,
    const int* __restrict__ rp, const int2* __restrict__ sse,
    const int* __restrict__ basep, const int* __restrict__ ncount,
    const float* __restrict__ tblA, const float* __restrict__ tblB,
    int cidx, _Float16* __restrict__ aggrc16) {
  int li = (blockIdx.x * 256 + threadIdx.x) >> 6;
  int lane = threadIdx.x & 63;
  if (li >= ncount[cidx]) return;
  v4f A0 = ((const v4f*)(tblA + 0 * DD))[lane];
  v4f A1 = ((const v4f*)(tblA + 1 * DD))[lane];
  v4f A2 = ((const v4f*)(tblA + 2 * DD))[lane];
  v4f A3 = ((const v4f*)(tblA + 3 * DD))[lane];
  v4f B0 = ((const v4f*)(tblB + 0 * DD))[lane];
  v4f B1 = ((const v4f*)(tblB + 1 * DD))[lane];
  v4f B2 = ((const v4f*)(tblB + 2 * DD))[lane];
  v4f B3 = ((const v4f*)(tblB + 3 * DD))[lane];
  int g = basep[cidx] + li;
  int beg = rp[g], end = rp[g + 1];
  v4f acc = {0.f, 0.f, 0.f, 0.f};
  int p = beg;
  for (; p + 4 <= end; p += 4) {
    int2 d0 = sse[p];
    int2 d1 = sse[p + 1];
    int2 d2 = sse[p + 2];
    int2 d3 = sse[p + 3];
    v4f a0 = __builtin_nontemporal_load(((const v4f*)(ea + (size_t)d0.y * DD)) + lane);
    v4f a1 = __builtin_nontemporal_load(((const v4f*)(ea + (size_t)d1.y * DD)) + lane);
    v4f a2 = __builtin_nontemporal_load(((const v4f*)(ea + (size_t)d2.y * DD)) + lane);
    v4f a3 = __builtin_nontemporal_load(((const v4f*)(ea + (size_t)d3.y * DD)) + lane);
    h4 x0 = ((const h4*)(g16 + (size_t)(d0.x & 0x00FFFFFF) * DD))[lane];
    h4 x1 = ((const h4*)(g16 + (size_t)(d1.x & 0x00FFFFFF) * DD))[lane];
    h4 x2 = ((const h4*)(g16 + (size_t)(d2.x & 0x00FFFFFF) * DD))[lane];
    h4 x3 = ((const h4*)(g16 + (size_t)(d3.x & 0x00FFFFFF) * DD))[lane];
    int m0 = ((unsigned)d0.x) >> 24, m1 = ((unsigned)d1.x) >> 24;
    int m2 = ((unsigned)d2.x) >> 24, m3 = ((unsigned)d3.x) >> 24;
    v4f Aa = (m0 & 2) ? ((m0 & 1) ? A3 : A2) : ((m0 & 1) ? A1 : A0);
    v4f Ba = (m0 & 2) ? ((m0 & 1) ? B3 : B2) : ((m0 & 1) ? B1 : B0);
    acc += relu4(Aa * __builtin_convertvector(x0, v4f) + Ba + a0);
    Aa = (m1 & 2) ? ((m1 & 1) ? A3 : A2) : ((m1 & 1) ? A1 : A0);
    Ba = (m1 & 2) ? ((m1 & 1) ? B3 : B2) : ((m1 & 1) ? B1 : B0);
    acc += relu4(Aa * __builtin_convertvector(x1, v4f) + Ba + a1);
    Aa = (m2 & 2) ? ((m2 & 1) ? A3 : A2) : ((m2 & 1) ? A1 : A0);
    Ba = (m2 & 2) ? ((m2 & 1) ? B3 : B2) : ((m2 & 1) ? B1 : B0);
    acc += relu4(Aa * __builtin_convertvector(x2, v4f) + Ba + a2);
    Aa = (m3 & 2) ? ((m3 & 1) ? A3 : A2) : ((m3 & 1) ? A1 : A0);
    Ba = (m3 & 2) ? ((m3 & 1) ? B3 : B2) : ((m3 & 1) ? B1 : B0);
    acc += relu4(Aa * __builtin_convertvector(x3, v4f) + Ba + a3);
  }
  for (; p < end; ++p) {
    int2 d0 = sse[p];
    v4f a0 = __builtin_nontemporal_load(((const v4f*)(ea + (size_t)d0.y * DD)) + lane);
    h4 x0 = ((const h4*)(g16 + (size_t)(d0.x & 0x00FFFFFF) * DD))[lane];
    int m0 = ((unsigned)d0.x) >> 24;
    v4f Aa = (m0 & 2) ? ((m0 & 1) ? A3 : A2) : ((m0 & 1) ? A1 : A0);
    v4f Ba = (m0 & 2) ? ((m0 & 1) ? B3 : B2) : ((m0 & 1) ? B1 : B0);
    acc += relu4(Aa * __builtin_convertvector(x0, v4f) + Ba + a0);
  }
  h4 ho;
  ho.x = (_Float16)acc.x; ho.y = (_Float16)acc.y;
  ho.z = (_Float16)acc.z; ho.w = (_Float16)acc.w;
  ((h4*)(aggrc16 + (size_t)li * DD))[lane] = ho;
}

// split-bf16 MFMA GEMM: acc[3][4] (48 rows x 64 cols per wave) = bias + zb(48x256) @ W(256x256)
__device__ __forceinline__ void gemm_frag(
    const float (*zb)[ZPAD], const __bf16* __restrict__ wf,
    const float* __restrict__ bias, f32x4 (&acc)[3][4], int w, int lane) {
  const int l4 = lane >> 4, l16 = lane & 15;
#pragma unroll
  for (int cg = 0; cg < 4; ++cg) {
    float bv = bias[w * 64 + cg * 16 + l16];
    f32x4 b4 = {bv, bv, bv, bv};
#pragma unroll
    for (int mg = 0; mg < 3; ++mg) acc[mg][cg] = b4;
  }
  for (int kk = 0; kk < 8; ++kk) {
    bf16x8 bh[4], bl[4];
#pragma unroll
    for (int cg = 0; cg < 4; ++cg) {
      const __bf16* p = wf + (((size_t)(kk * 16 + w * 4 + cg)) * 64 + lane) * 8;
      bh[cg] = *(const bf16x8*)p;
      bl[cg] = *(const bf16x8*)(p + 65536);
    }
#pragma unroll
    for (int mg = 0; mg < 3; ++mg) {
      const float* zp = &zb[mg * 16 + l16][kk * 32 + l4 * 8];
      float4 z0 = *(const float4*)zp;
      float4 z1 = *(const float4*)(zp + 4);
      float zv[8] = {z0.x, z0.y, z0.z, z0.w, z1.x, z1.y, z1.z, z1.w};
      bf16x8 ah, al;
#pragma unroll
      for (int j = 0; j < 8; ++j) {
        __bf16 h = (__bf16)zv[j];
        ah[j] = h;
        al[j] = (__bf16)(zv[j] - (float)h);
      }
#pragma unroll
      for (int cg = 0; cg < 4; ++cg) {
        acc[mg][cg] = __builtin_amdgcn_mfma_f32_16x16x32_bf16(al, bh[cg], acc[mg][cg], 0, 0, 0);
        acc[mg][cg] = __builtin_amdgcn_mfma_f32_16x16x32_bf16(ah, bl[cg], acc[mg][cg], 0, 0, 0);
        acc[mg][cg] = __builtin_amdgcn_mfma_f32_16x16x32_bf16(ah, bh[cg], acc[mg][cg], 0, 0, 0);
      }
    }
  }
}

// Masked-rows MLP for pass c. Cluster-c rows are unhit: x_c = P*x0 + Q (x0 = x_in, fp32).
// z=(1+eps)x_c+aggr; t=relu(z@W1+b1); h=t@W2+b2; v = x_c + h (pre-norm y).
// Writes xbase[nid]=v (fp32), g16[nid]=fp16(v); accumulates sum(v), sum(v^2) into sv1,sv2.
__global__ __launch_bounds__(256, 2) void k_mlp_m(
    const float* __restrict__ xin, const _Float16* __restrict__ aggrc16,
    float* __restrict__ xbase, _Float16* __restrict__ g16,
    const __bf16* __restrict__ wf1, const __bf16* __restrict__ wf2,
    const float* __restrict__ b1g, const float* __restrict__ b2g,
    const int* __restrict__ nlist_c, const int* __restrict__ ncnt_c,
    const float* __restrict__ epsp, const float* __restrict__ Pg,
    const float* __restrict__ Qg,
    float* __restrict__ sv1c, float* __restrict__ sv2c) {
  __shared__ __align__(16) float zbuf[MROWS][ZPAD];
  __shared__ float ssum[DD];
  __shared__ float ssq[DD];
  __shared__ int nls[MROWS];
  const int t = threadIdx.x;
  const int lane = t & 63, w = t >> 6;
  const int l4 = lane >> 4, l16 = lane & 15;
  const int ncnt = *ncnt_c;
  const int li0 = blockIdx.x * MROWS;
  if (li0 >= ncnt) return;
  if (t < MROWS) nls[t] = (li0 + t < ncnt) ? nlist_c[li0 + t] : -1;
  ssum[t] = 0.f;
  ssq[t] = 0.f;
  const float ep = 1.0f + epsp[0];
  __syncthreads();
  // stage z = ep*(P*x0+Q) + aggr (coalesced; aggr fp16)
  const int c4s = (t & 63) << 2;
  const float4 Pv4 = *(const float4*)(Pg + c4s);
  const float4 Qv4 = *(const float4*)(Qg + c4s);
#pragma unroll
  for (int i = 0; i < 12; ++i) {
    int f4 = t + 256 * i;  // 3072 float4 = 48x256
    int r = f4 >> 6;
    int nid = nls[r];
    float4 zv = make_float4(0.f, 0.f, 0.f, 0.f);
    if (nid >= 0) {
      float4 xv = *(const float4*)(xin + (size_t)nid * DD + c4s);
      h4 ah = *(const h4*)(aggrc16 + (size_t)(li0 + r) * DD + c4s);
      v4f av = __builtin_convertvector(ah, v4f);
      zv.x = fmaf(ep, fmaf(Pv4.x, xv.x, Qv4.x), av.x);
      zv.y = fmaf(ep, fmaf(Pv4.y, xv.y, Qv4.y), av.y);
      zv.z = fmaf(ep, fmaf(Pv4.z, xv.z, Qv4.z), av.z);
      zv.w = fmaf(ep, fmaf(Pv4.w, xv.w, Qv4.w), av.w);
    }
    *(float4*)&zbuf[r][c4s] = zv;
  }
  __syncthreads();
  f32x4 acc[3][4];
  gemm_frag(zbuf, wf1, b1g, acc, w, lane);
  __syncthreads();  // all zbuf reads of GEMM1 done
  // t = relu(.) written back to zbuf (D layout: row=(l>>4)*4+r, col=l&15)
#pragma unroll
  for (int mg = 0; mg < 3; ++mg)
#pragma unroll
    for (int cg = 0; cg < 4; ++cg)
#pragma unroll
      for (int r = 0; r < 4; ++r)
        zbuf[mg * 16 + l4 * 4 + r][w * 64 + cg * 16 + l16] = fmaxf(acc[mg][cg][r], 0.f);
  __syncthreads();
  f32x4 acc2[3][4];
  gemm_frag(zbuf, wf2, b2g, acc2, w, lane);
  // epilogue: v = (P*x0+Q) + h; write xbase/g16; sums of v, v^2
  float Pv[4], Qv[4], ps[4], pq[4];
#pragma unroll
  for (int cg = 0; cg < 4; ++cg) {
    int col = w * 64 + cg * 16 + l16;
    Pv[cg] = Pg[col];
    Qv[cg] = Qg[col];
    ps[cg] = 0.f;
    pq[cg] = 0.f;
  }
#pragma unroll
  for (int mg = 0; mg < 3; ++mg) {
#pragma unroll
    for (int r = 0; r < 4; ++r) {
      int rb = mg * 16 + l4 * 4 + r;
      int nid = nls[rb];
      if (nid >= 0) {
#pragma unroll
        for (int cg = 0; cg < 4; ++cg) {
          int col = w * 64 + cg * 16 + l16;
          float x0v = xin[(size_t)nid * DD + col];
          float xcv = fmaf(Pv[cg], x0v, Qv[cg]);
          float v = xcv + acc2[mg][cg][r];
          xbase[(size_t)nid * DD + col] = v;
          g16[(size_t)nid * DD + col] = (_Float16)v;
          ps[cg] += v;
          pq[cg] += v * v;
        }
      }
    }
  }
#pragma unroll
  for (int cg = 0; cg < 4; ++cg) {
    atomicAdd(&ssum[w * 64 + cg * 16 + l16], ps[cg]);
    atomicAdd(&ssq[w * 64 + cg * 16 + l16], pq[cg]);
  }
  __syncthreads();
  atomicAdd(&sv1c[t], ssum[t]);
  atomicAdd(&sv2c[t], ssq[t]);
}

// Per-pass BN stats from composed group sums + affine-chain update. 1 block, DD threads.
__global__ void k_stats(const float* __restrict__ s01, const float* __restrict__ s02,
                        const float* __restrict__ sv1, const float* __restrict__ sv2,
                        const int* __restrict__ ncount,
                        const float* __restrict__ gamma_c, const float* __restrict__ beta_c,
                        float* __restrict__ Pg, float* __restrict__ Qg,
                        float* __restrict__ Rg, float* __restrict__ Sg,
                        float* __restrict__ tblA, float* __restrict__ tblB, int c) {
  int d = threadIdx.x;
  float Pd = Pg[d], Qd = Qg[d];
  float sum = 0.f, ssq = 0.f;
#pragma unroll
  for (int m = 0; m < CC; ++m) {
    float n = (float)ncount[m];
    if (m < c) {
      float A = Rg[m * DD + d], B = Sg[m * DD + d];
      sum += fmaf(A, sv1[m * DD + d], n * B);
      ssq += A * A * sv2[m * DD + d] + 2.f * A * B * sv1[m * DD + d] + n * B * B;
    } else if (m == c) {
      sum += sv1[m * DD + d];
      ssq += sv2[m * DD + d];
    } else {
      sum += fmaf(Pd, s01[m * DD + d], n * Qd);
      ssq += Pd * Pd * s02[m * DD + d] + 2.f * Pd * Qd * s01[m * DD + d] + n * Qd * Qd;
    }
  }
  const float inv_n = 1.0f / (float)NN;
  float mean = sum * inv_n;
  float var = fmaxf(ssq * inv_n - mean * mean, 0.f);
  float sc = gamma_c[d] * rsqrtf(var + BN_EPSF);
  float sh = fmaf(-mean, sc, beta_c[d]);
  // update chains (x_{c+1} = sc*y_c + sh)
  float Pn = sc * Pd, Qn = fmaf(sc, Qd, sh);
  Pg[d] = Pn;
  Qg[d] = Qn;
#pragma unroll
  for (int m = 0; m < CC; ++m) {
    if (m < c) {
      float Rn = sc * Rg[m * DD + d];
      float Sn = fmaf(sc, Sg[m * DD + d], sh);
      Rg[m * DD + d] = Rn;
      Sg[m * DD + d] = Sn;
      tblA[m * DD + d] = Rn;
      tblB[m * DD + d] = Sn;
    } else if (m == c) {
      Rg[m * DD + d] = sc;
      Sg[m * DD + d] = sh;
      tblA[m * DD + d] = sc;
      tblB[m * DD + d] = sh;
    } else {
      tblA[m * DD + d] = Pn;
      tblB[m * DD + d] = Qn;
    }
  }
}

// final: out = x_in + relu(R_m * v + S_m)  (all nodes hit; tbl holds R,S after pass 3)
__global__ __launch_bounds__(256) void k_final(
    const float* __restrict__ xbase, const int* __restrict__ pcl,
    const float* __restrict__ tblA, const float* __restrict__ tblB,
    const float* __restrict__ xin, float* __restrict__ outp) {
  const int t = threadIdx.x;
  const int lane = t & 63;
  const int wid0 = (blockIdx.x * 256 + t) >> 6;
  const int wstride = gridDim.x * 4;
  for (int i = wid0; i < NN; i += wstride) {
    int m = ((unsigned)pcl[i]) >> 28;
    v4f v = ((const v4f*)(xbase + (size_t)i * DD))[lane];
    v4f A = ((const v4f*)(tblA + (size_t)m * DD))[lane];
    v4f B = ((const v4f*)(tblB + (size_t)m * DD))[lane];
    v4f xi = ((const v4f*)(xin + (size_t)i * DD))[lane];
    ((v4f*)(outp + (size_t)i * DD))[lane] = xi + relu4(A * v + B);
  }
}

// ---------------- launch ----------------

extern "C" void kernel_launch(void* const* d_in, const int* in_sizes, int n_in,
                              void* d_out, int out_size, void* d_ws, size_t ws_size,
                              hipStream_t stream) {
  (void)in_sizes; (void)n_in; (void)out_size; (void)ws_size;
  const float* x_in  = (const float*)d_in[0];
  const int*   ei    = (const int*)d_in[1];
  const float* ea    = (const float*)d_in[2];
  const float* masks = (const float*)d_in[3];
  // d_in[4] = complement_masks: unused by the reference
  const float* W1    = (const float*)d_in[5];
  const float* b1    = (const float*)d_in[6];
  const float* W2    = (const float*)d_in[7];
  const float* b2    = (const float*)d_in[8];
  const float* eps   = (const float*)d_in[9];
  const float* gamma = (const float*)d_in[10];
  const float* beta  = (const float*)d_in[11];
  float* out = (float*)d_out;

  // workspace layout (all 16B-aligned); ~115 MB
  float* xbase = (float*)d_ws;                        // NN*DD (per-node pre-norm y_m)
  _Float16* g16 = (_Float16*)(xbase + (size_t)NN * DD);  // NN*DD fp16 gather base
  _Float16* aggrc16 = g16 + (size_t)NN * DD;          // NN*DD fp16 compact aggregates
  int2*  sse   = (int2*)(aggrc16 + (size_t)NN * DD);  // EE ((cl<<24)|src, e) per slot
  int*   rp    = (int*)(sse + EE);                    // NN+1 (padded to 50016)
  int*   cnt   = rp + 50016;                          // NN (padded), also scatter cursor
  int*   nlist = cnt + 50016;                         // CC*NN (compacted node lists)
  int*   pcl   = nlist + CC * NN;                     // NN packed (c<<28)|listpos
  int*   ncount = pcl + NN;                           // CC (padded to 16)
  int*   base  = ncount + 16;                         // CC (padded to 16)
  float* s01   = (float*)(base + 16);                 // CC*DD sum(x0) per cluster
  float* s02   = s01 + CC * DD;                       // CC*DD sum(x0^2)
  float* sv1   = s02 + CC * DD;                       // CC*DD sum(v_m)
  float* sv2   = sv1 + CC * DD;                       // CC*DD sum(v_m^2)
  float* Pg    = sv2 + CC * DD;                       // DD unhit-chain scale
  float* Qg    = Pg + DD;                             // DD unhit-chain shift
  float* Rg    = Qg + DD;                             // CC*DD hit-chain scale
  float* Sg    = Rg + CC * DD;                        // CC*DD hit-chain shift
  float* tblA  = Sg + CC * DD;                        // CC*DD aggregate coeff A
  float* tblB  = tblA + CC * DD;                      // CC*DD aggregate coeff B
  __bf16* wfmt = (__bf16*)(tblB + CC * DD);           // 4*2*2*65536 bf16 = 2 MB

  const int* src = ei;
  const int* dst = ei + EE;

  hipMemsetAsync(cnt, 0, NN * sizeof(int), stream);
  hipMemsetAsync(ncount, 0, 32 * sizeof(int), stream);
  hipMemsetAsync(s01, 0, 4 * CC * DD * sizeof(float), stream);  // s01,s02,sv1,sv2

  k_wfmt<<<64, 256, 0, stream>>>(W1, W2, wfmt);
  k_compact<<<(NN + 255) / 256, 256, 0, stream>>>(masks, ncount, nlist, pcl);
  k_setup<<<1, DD, 0, stream>>>(ncount, base, Pg, Qg, tblA, tblB);
  k_hist<<<EE / 256, 256, 0, stream>>>(dst, pcl, base, cnt);
  k_scan<<<1, 1024, 0, stream>>>(cnt, rp);
  k_scatter<<<EE / 256, 256, 0, stream>>>(src, dst, pcl, base, cnt, sse);
  k_prep<<<256, 256, 0, stream>>>(x_in, pcl, g16, s01, s02);

  for (int c = 0; c < CC; ++c) {
    k_aggregate_m<<<(NN * 64 + 255) / 256, 256, 0, stream>>>(
        g16, ea, rp, sse, base, ncount, tblA, tblB, c, aggrc16);
    k_mlp_m<<<(NN + MROWS - 1) / MROWS, 256, 0, stream>>>(
        x_in, aggrc16, xbase, g16,
        wfmt + (size_t)(c * 2 + 0) * 2 * 65536,
        wfmt + (size_t)(c * 2 + 1) * 2 * 65536,
        b1 + (size_t)c * DD, b2 + (size_t)c * DD,
        nlist + c * NN, ncount + c, eps + c, Pg, Qg,
        sv1 + c * DD, sv2 + c * DD);
    k_stats<<<1, DD, 0, stream>>>(s01, s02, sv1, sv2, ncount,
                                  gamma + (size_t)c * DD, beta + (size_t)c * DD,
                                  Pg, Qg, Rg, Sg, tblA, tblB, c);
  }
  k_final<<<512, 256, 0, stream>>>(xbase, pcl, tblA, tblB, x_in, out);
}